// Round 1
// baseline (66.999 us; speedup 1.0000x reference)
//
#include <hip/hip_runtime.h>
#include <math.h>

#define T 8192
#define D 128
#define R 24                   // tail beyond 24 is < 1e-10 of psedu scale for sigma_max=4
#define NT (2 * R + 1)         // 49 taps
#define NTP 52                 // taps padded to float4 multiple
#define BLK 512                // one workgroup, 8 waves on one CU
#define OPT 16                 // outputs per thread: 512*16 = 8192
#define MPAD 32                // zero-pad each side so every window read is aligned+in-bounds
#define MSZ (T + 2 * MPAD)     // 8256 floats, multiple of 32 (swizzle containment)
#define NSLOT (MSZ / 4)        // 2064 float4 slots
#define WREG 80                // per-thread register window: [16*tid-32, 16*tid+48)

// XOR swizzle on 4-aligned float index: spreads bits[4:2] (bank group) with bits[7:5].
// Bijective within each 32-float block; applied identically on LDS write and read, so
// both the stride-16B staging writes and the stride-64B window reads hit the 8-cycle
// conflict-free floor (8 distinct rows per bank group).
__device__ __forceinline__ int swz(int f) { return f ^ (((f >> 5) & 7) << 2); }

// Single-workgroup fused kernel: no device-scope barrier, no workspace, no redundant
// per-block table computation. Global min/max is a plain block reduction.
__global__ __launch_bounds__(BLK) void CAGKE_fused_kernel(
    const float* __restrict__ X,
    const float* __restrict__ weight,
    const float* __restrict__ sigma_min,
    const float* __restrict__ sigma_max,
    const float* __restrict__ noise,
    float* __restrict__ out)
{
    __shared__ __align__(16) float lds_m[MSZ];   // swizzled mask image, pos = f - MPAD
    __shared__ float coef[D];                    // weight, then softmax(w)_d * c_d
    __shared__ float nexp[D];                    // -1/(2 s_d^2)
    __shared__ __align__(16) float s_table[NTP]; // F(delta), padded with zeros
    __shared__ float part[NT][4];                // table partials
    __shared__ float red[16];
    __shared__ float s_w[2];                     // softmax max, denom

    const int tid = threadIdx.x;
    const int t0  = tid * OPT;

    // ---- issue independent global loads early ----
    float4 nzv[4];
#pragma unroll
    for (int k = 0; k < 4; ++k)
        nzv[k] = *reinterpret_cast<const float4*>(&noise[t0 + 4 * k]);

    if (tid < D) coef[tid] = weight[tid];

    // ---- stage mask into swizzled LDS (X is 0/1 float; mask == (X>0.5)) ----
    // slot idx covers float positions p = 4*idx - MPAD .. +3.
    // idx in [8, 2055] is fully in-bounds (16B aligned); idx<8 / idx>=2056 are pure pad.
    for (int idx = tid; idx < NSLOT; idx += BLK) {
        float4 v = make_float4(0.f, 0.f, 0.f, 0.f);
        if (idx >= 8 && idx <= 2055) {
            const float4 x = *reinterpret_cast<const float4*>(&X[4 * idx - MPAD]);
            v.x = (x.x > 0.5f) ? 1.f : 0.f;
            v.y = (x.y > 0.5f) ? 1.f : 0.f;
            v.z = (x.z > 0.5f) ? 1.f : 0.f;
            v.w = (x.w > 0.5f) ? 1.f : 0.f;
        }
        *reinterpret_cast<float4*>(&lds_m[swz(4 * idx)]) = v;
    }
    __syncthreads();

    // ---- softmax denom: wave 0 shuffle-reduces 128 weights ----
    if (tid < 64) {
        float a = fmaxf(coef[tid], coef[tid + 64]);
        for (int off = 32; off; off >>= 1) a = fmaxf(a, __shfl_down(a, off, 64));
        const float mx = __shfl(a, 0, 64);
        float e = __expf(coef[tid] - mx) + __expf(coef[tid + 64] - mx);
        for (int off = 32; off; off >>= 1) e += __shfl_down(e, off, 64);
        if (tid == 0) { s_w[0] = mx; s_w[1] = e; }
    }
    __syncthreads();

    // ---- per-d constants ----
    if (tid < D) {
        const float wmx  = s_w[0];
        const float winv = 1.f / s_w[1];
        const float smin = sigma_min[0];
        const float smax = sigma_max[0];
        const float step = (smax - smin) / (float)(D - 1);
        const float s  = fabsf(smin + (float)tid * step);
        const float pw = __expf(coef[tid] - wmx) * winv;
        nexp[tid] = -0.5f / (s * s);
        coef[tid] = pw * (0.39894228f / s);
    }
    __syncthreads();

    // ---- F table: 49 entries, each split over 4 threads (32-iter partials) ----
    if (tid < 4 * NT) {
        const int i = tid >> 2, q = tid & 3;
        const float delta = (float)(i - R);
        const float d2 = delta * delta;
        const int d0 = q * 32;
        float acc = 0.f;
#pragma unroll 8
        for (int dd = 0; dd < 32; ++dd) {
            const int d = d0 + dd;
            acc += coef[d] * __expf(d2 * nexp[d]);
        }
        part[i][q] = acc;
    }
    __syncthreads();
    if (tid < NTP)
        s_table[tid] = (tid < NT)
            ? (part[tid][0] + part[tid][1]) + (part[tid][2] + part[tid][3])
            : 0.f;
    __syncthreads();

    // ---- register-blocked 49-tap FIR: 16 outputs/thread ----
    // window: positions [16*tid - 32, 16*tid + 48) -> lds float index f = 16*tid + 4k
    float w[WREG];
#pragma unroll
    for (int k = 0; k < WREG / 4; ++k) {
        const float4 v = *reinterpret_cast<const float4*>(&lds_m[swz(16 * tid + 4 * k)]);
        w[4 * k + 0] = v.x; w[4 * k + 1] = v.y; w[4 * k + 2] = v.z; w[4 * k + 3] = v.w;
    }

    float tb[NTP];
#pragma unroll
    for (int k = 0; k < NTP / 4; ++k) {
        const float4 v = *reinterpret_cast<const float4*>(&s_table[4 * k]);
        tb[4 * k + 0] = v.x; tb[4 * k + 1] = v.y; tb[4 * k + 2] = v.z; tb[4 * k + 3] = v.w;
    }

    // psedu[t] = sum_j table[j] * mask[t - 1 - R + j]  (table is symmetric in j<->2R-j,
    // bitwise: both entries use the same (i-R)^2)  ->  w index = r + 7 + j, max 70 < 80
    float acc[OPT];
#pragma unroll
    for (int r = 0; r < OPT; ++r) acc[r] = 0.f;
#pragma unroll
    for (int j = 0; j < NT; ++j) {
        const float tv = tb[j];
#pragma unroll
        for (int r = 0; r < OPT; ++r)
            acc[r] = fmaf(tv, w[r + 7 + j], acc[r]);
    }

    // ---- add noise, block min/max over all 8192 values ----
    float lo = INFINITY, hi = -INFINITY;
#pragma unroll
    for (int k = 0; k < 4; ++k) {
        acc[4 * k + 0] += 0.01f * nzv[k].x;
        acc[4 * k + 1] += 0.01f * nzv[k].y;
        acc[4 * k + 2] += 0.01f * nzv[k].z;
        acc[4 * k + 3] += 0.01f * nzv[k].w;
    }
#pragma unroll
    for (int r = 0; r < OPT; ++r) {
        lo = fminf(lo, acc[r]);
        hi = fmaxf(hi, acc[r]);
    }
    for (int off = 32; off; off >>= 1) {
        lo = fminf(lo, __shfl_down(lo, off, 64));
        hi = fmaxf(hi, __shfl_down(hi, off, 64));
    }
    const int wave = tid >> 6, lane = tid & 63;
    if (lane == 0) { red[wave] = lo; red[8 + wave] = hi; }
    __syncthreads();
    if (tid == 0) {
        float l = red[0], h = red[8];
#pragma unroll
        for (int i = 1; i < 8; ++i) {
            l = fminf(l, red[i]);
            h = fmaxf(h, red[8 + i]);
        }
        red[0] = l; red[1] = h;
    }
    __syncthreads();

    const float glo = red[0];
    const float inv = 1.f / (red[1] - glo);
#pragma unroll
    for (int k = 0; k < 4; ++k) {
        float4 o;
        o.x = (acc[4 * k + 0] - glo) * inv;
        o.y = (acc[4 * k + 1] - glo) * inv;
        o.z = (acc[4 * k + 2] - glo) * inv;
        o.w = (acc[4 * k + 3] - glo) * inv;
        *reinterpret_cast<float4*>(&out[t0 + 4 * k]) = o;
    }
}

extern "C" void kernel_launch(void* const* d_in, const int* in_sizes, int n_in,
                              void* d_out, int out_size, void* d_ws, size_t ws_size,
                              hipStream_t stream) {
    const float* X     = (const float*)d_in[0];
    const float* wgt   = (const float*)d_in[1];
    const float* smin  = (const float*)d_in[2];
    const float* smax  = (const float*)d_in[3];
    const float* noise = (const float*)d_in[4];
    float* out = (float*)d_out;
    (void)d_ws; (void)ws_size;

    CAGKE_fused_kernel<<<1, BLK, 0, stream>>>(X, wgt, smin, smax, noise, out);
}